// Round 5
// baseline (235.042 us; speedup 1.0000x reference)
//
#include <hip/hip_runtime.h>

typedef _Float16 v8h __attribute__((ext_vector_type(8)));
typedef _Float16 v4h __attribute__((ext_vector_type(4)));
typedef float v4f __attribute__((ext_vector_type(4)));
#define HF _Float16

// dims
#define Bn 8
#define Cc 512
#define CI 256
#define HW 4096   // 64*64
#define Mp 1024   // 32*32 pooled

__device__ __forceinline__ void gload16(const void* g, void* l) {
    __builtin_amdgcn_global_load_lds((const __attribute__((address_space(1))) void*)g,
                                     (__attribute__((address_space(3))) void*)l, 16, 0, 0);
}

// ---------------- prep: weights fp32->f16, BN fold ----------------
__global__ __launch_bounds__(256) void prep_kernel(
    const float* __restrict__ w_g, const float* __restrict__ b_g,
    const float* __restrict__ w_th, const float* __restrict__ b_th,
    const float* __restrict__ w_ph, const float* __restrict__ b_ph,
    const float* __restrict__ w_out, const float* __restrict__ b_out,
    const float* __restrict__ gamma, const float* __restrict__ beta,
    const float* __restrict__ mean, const float* __restrict__ var,
    HF* __restrict__ wall, float* __restrict__ ball,
    HF* __restrict__ wo, float* __restrict__ scale, float* __restrict__ shift)
{
    int idx = blockIdx.x * 256 + threadIdx.x;
    if (idx < 768*512) {
        int o = idx >> 9;
        float v = (o < 256) ? w_th[idx] : (o < 512) ? w_ph[idx - 256*512] : w_g[idx - 512*512];
        wall[idx] = (HF)v;
    }
    if (idx < 512*256) wo[idx] = (HF)w_out[idx];
    if (idx < 768) ball[idx] = (idx < 256) ? b_th[idx] : (idx < 512) ? b_ph[idx-256] : b_g[idx-512];
    if (idx < 512) {
        float inv = gamma[idx] * rsqrtf(var[idx] + 1e-5f);
        scale[idx] = inv;
        shift[idx] = (b_out[idx] - mean[idx]) * inv + beta[idx];
    }
}

// ---------------- transpose x: (b,c,s) fp32 -> xT (b,s,c) f16 ----------------
__global__ __launch_bounds__(256) void transpose_x_kernel(const float* __restrict__ x, HF* __restrict__ xT)
{
    __shared__ float tile[64][65];
    int b = blockIdx.z;
    int c0 = blockIdx.y * 64, s0 = blockIdx.x * 64;
    int tr = threadIdx.x >> 6, ts = threadIdx.x & 63;
    #pragma unroll
    for (int i = 0; i < 16; ++i) {
        int r = tr + i*4;
        tile[r][ts] = x[((long)(b*Cc) + c0 + r)*HW + s0 + ts];
    }
    __syncthreads();
    #pragma unroll
    for (int i = 0; i < 16; ++i) {
        int r = tr + i*4;
        xT[((long)b*HW + s0 + r)*Cc + c0 + ts] = (HF)tile[ts][r];
    }
}

// ---------------- generic f16 transpose per batch: src[R][Cn] -> dst[Cn][R] ----------------
__global__ __launch_bounds__(256) void transpose_h_kernel(const HF* __restrict__ src, long sSrc,
                                                          HF* __restrict__ dst, long sDst,
                                                          int R, int Cn)
{
    __shared__ HF tile[64][65];
    int b = blockIdx.z;
    int r0 = blockIdx.y * 64, c0 = blockIdx.x * 64;
    const HF* S = src + (long)b * sSrc;
    HF* D = dst + (long)b * sDst;
    int tr = threadIdx.x >> 6, tc = threadIdx.x & 63;
    #pragma unroll
    for (int i = 0; i < 16; ++i) {
        int r = tr + i*4;
        tile[r][tc] = S[(long)(r0 + r)*Cn + c0 + tc];
    }
    __syncthreads();
    #pragma unroll
    for (int i = 0; i < 16; ++i) {
        int r = tr + i*4;
        D[(long)(c0 + r)*R + r0 + tc] = tile[tc][r];
    }
}

// ---------------- 2x2 maxpool: src (b,c,64,64) -> dst (b,c,32,32) ----------------
__global__ __launch_bounds__(256) void pool_kernel(const HF* __restrict__ src, long sSrc,
                                                   HF* __restrict__ dst, long sDst)
{
    long idx = (long)blockIdx.x * 256 + threadIdx.x;   // Bn*256*1024
    int m = idx & 1023;
    long bc = idx >> 10;
    int c = (int)(bc & 255);
    int b = (int)(bc >> 8);
    int h2 = m >> 5, w2 = m & 31;
    const HF* p = src + (long)b*sSrc + (long)c*HW + h2*128 + w2*2;
    float v = fmaxf(fmaxf((float)p[0], (float)p[1]), fmaxf((float)p[64], (float)p[65]));
    dst[(long)b*sDst + (long)c*Mp + m] = (HF)v;
}

// ---------------- generic tiled gemm_bt: C[i,j] = sum_k A[i,k]*B[j,k] ----------------
// gload_lds staged, double-buffered. LDS layout [kg][128][8] (k-group-major):
// gload dest linear (kg wave-uniform), ds_read b128 = 16 consecutive 16B -> conflict-free.
template<int EPI>
__global__ __launch_bounds__(256) void gemm_bt_kernel(
    const HF* __restrict__ A, long sA, const HF* __restrict__ B, long sB,
    void* __restrict__ Cv, long sC, int M, int N, int K,
    const float* __restrict__ rowBias,
    const float* __restrict__ rowScale, const float* __restrict__ rowShift,
    const float* __restrict__ Xres, long sX)
{
    __shared__ alignas(16) HF As[2][4096];   // [4 kg][128 row][8]
    __shared__ alignas(16) HF Bs[2][4096];
    int b = blockIdx.z;
    int i0 = blockIdx.y * 128;
    int j0 = blockIdx.x * 128;
    const HF* Ab = A + (long)b * sA;
    const HF* Bb = B + (long)b * sB;
    int tid = threadIdx.x;
    int lane = tid & 63, w = tid >> 6;
    int wr = w >> 1, wc = w & 1;
    int lr = lane & 15, lkg = lane >> 4;

    auto stage = [&](int bsel, int k0) {
        #pragma unroll
        for (int q = 0; q < 2; ++q) {
            int idx = q*256 + tid;           // 0..511; dest = idx*16B, kg wave-uniform
            int kg = idx >> 7, row = idx & 127;
            gload16(Ab + (long)(i0+row)*K + k0 + kg*8, As[bsel] + (size_t)idx*8);
            gload16(Bb + (long)(j0+row)*K + k0 + kg*8, Bs[bsel] + (size_t)idx*8);
        }
    };

    v4f acc[4][4];
    #pragma unroll
    for (int i = 0; i < 4; ++i)
        #pragma unroll
        for (int j = 0; j < 4; ++j) { v4f z = {0.f,0.f,0.f,0.f}; acc[i][j] = z; }

    stage(0, 0);
    __syncthreads();
    int cur = 0;
    for (int k0 = 0; k0 < K; k0 += 32) {
        if (k0 + 32 < K) stage(cur ^ 1, k0 + 32);
        v8h af[4], bfr[4];
        #pragma unroll
        for (int mf = 0; mf < 4; ++mf)
            af[mf] = *(const v8h*)(As[cur] + lkg*1024 + (wr*64 + mf*16 + lr)*8);
        #pragma unroll
        for (int nf = 0; nf < 4; ++nf)
            bfr[nf] = *(const v8h*)(Bs[cur] + lkg*1024 + (wc*64 + nf*16 + lr)*8);
        __builtin_amdgcn_s_setprio(1);
        #pragma unroll
        for (int mf = 0; mf < 4; ++mf)
            #pragma unroll
            for (int nf = 0; nf < 4; ++nf)
                acc[mf][nf] = __builtin_amdgcn_mfma_f32_16x16x32_f16(af[mf], bfr[nf], acc[mf][nf], 0, 0, 0);
        __builtin_amdgcn_s_setprio(0);
        __syncthreads();     // barrier drains vmcnt: next buffer staged, cur reads done
        cur ^= 1;
    }

    int rbase = (lane >> 4) * 4;
    #pragma unroll
    for (int mf = 0; mf < 4; ++mf) {
        #pragma unroll
        for (int nf = 0; nf < 4; ++nf) {
            #pragma unroll
            for (int r = 0; r < 4; ++r) {
                int row = i0 + wr*64 + mf*16 + rbase + r;
                int col = j0 + wc*64 + nf*16 + lr;
                float v = acc[mf][nf][r];
                if (EPI == 0) {
                    v += rowBias[row];
                    ((HF*)Cv + (long)b*sC)[(long)row*N + col] = (HF)v;
                } else {
                    float* Cf = (float*)Cv + (long)b*sC;
                    const float* Xb = Xres + (long)b*sX;
                    long o = (long)row*N + col;
                    Cf[o] = v * rowScale[row] + rowShift[row] + Xb[o];
                }
            }
        }
    }
}

// ---------------- fused flash attention v4 ----------------
// 512 blocks, 4 waves x 16 rows, m-chunks of 32, double-buffered gload_lds.
// LDS k-group-major ([kg][rows][8]) -> all MFMA fragment reads conflict-free, no swizzle.
// Online softmax: per-row max butterfly only; rescale conditional (rare);
// per-lane partial sums, single reduce at end. p = exp(S - rowmax) <= 1 -> f16 safe.
__global__ __launch_bounds__(256, 2) void fused_attn_kernel(
    const HF* __restrict__ Tt,   // [B][4096][256]
    const HF* __restrict__ Pt,   // [B][1024][256]
    const HF* __restrict__ G,    // [B][256][1024]
    HF* __restrict__ Yt)         // [B][4096][256]
{
    __shared__ alignas(16) HF P_lds[2][8192];   // [32 kg][32 row][8]
    __shared__ alignas(16) HF G_lds[2][8192];   // [4 kg][256 row][8]
    __shared__ alignas(16) HF P_buf[4][16][36]; // padded stride 72B

    int b = blockIdx.y;
    int tid = threadIdx.x;
    int lane = tid & 63, w = tid >> 6;
    int lr = lane & 15, lkg = lane >> 4;
    int nbase = blockIdx.x * 64 + w * 16;

    const HF* Tb = Tt + ((long)b*HW + nbase) * CI;
    const HF* Pb = Pt + (long)b*Mp*CI;
    const HF* Gb = G  + (long)b*CI*Mp;

    auto stage = [&](int bsel, int m0) {
        #pragma unroll
        for (int q = 0; q < 4; ++q) {
            int idxp = (w*4 + q)*64 + lane;         // 0..1023; dest = idxp*16B
            int pkg = idxp >> 5, prow = idxp & 31;  // [32 kg][32 row][8]
            gload16(Pb + (long)(m0 + prow)*CI + pkg*8, P_lds[bsel] + (size_t)idxp*8);
            int grow = q*64 + lane;                 // kg = w (wave-uniform)
            gload16(Gb + (long)grow*Mp + m0 + w*8, G_lds[bsel] + ((size_t)w*256 + grow)*8);
        }
    };

    // Q fragments in registers for whole kernel
    v8h af[8];
    #pragma unroll
    for (int kf = 0; kf < 8; ++kf)
        af[kf] = *(const v8h*)(Tb + (long)lr*CI + kf*32 + lkg*8);

    v4f acc_y[16];
    #pragma unroll
    for (int i = 0; i < 16; ++i) { v4f z = {0.f,0.f,0.f,0.f}; acc_y[i] = z; }
    float mrun[4] = {-1e30f,-1e30f,-1e30f,-1e30f};
    float lsum[4] = {0.f,0.f,0.f,0.f};

    stage(0, 0);
    __syncthreads();

    int cur = 0;
    for (int t = 0; t < 32; ++t) {
        if (t < 31) stage(cur ^ 1, (t+1)*32);

        // QK^T: S[16 n][32 m]
        v4f acc[2];
        #pragma unroll
        for (int nf = 0; nf < 2; ++nf) { v4f z = {0.f,0.f,0.f,0.f}; acc[nf] = z; }
        __builtin_amdgcn_s_setprio(1);
        #pragma unroll
        for (int kf = 0; kf < 8; ++kf) {
            #pragma unroll
            for (int nf = 0; nf < 2; ++nf) {
                v8h bfr = *(const v8h*)(P_lds[cur] + (kf*4 + lkg)*256 + (nf*16 + lr)*8);
                acc[nf] = __builtin_amdgcn_mfma_f32_16x16x32_f16(af[kf], bfr, acc[nf], 0, 0, 0);
            }
        }
        __builtin_amdgcn_s_setprio(0);

        // online softmax: max butterfly always; rescale only when row max grows
        #pragma unroll
        for (int r = 0; r < 4; ++r) {
            float cm = fmaxf(acc[0][r], acc[1][r]);
            #pragma unroll
            for (int d = 1; d < 16; d <<= 1) cm = fmaxf(cm, __shfl_xor(cm, d));
            if (cm > mrun[r]) {                       // identical across the row's 16 lanes
                float alpha = __expf(mrun[r] - cm);   // first time: exp(-1e30)=0, zeroes nothing
                mrun[r] = cm;
                lsum[r] *= alpha;
                #pragma unroll
                for (int cf = 0; cf < 16; ++cf) acc_y[cf][r] *= alpha;
            }
            int row = lkg*4 + r;
            #pragma unroll
            for (int nf = 0; nf < 2; ++nf) {
                float p = __expf(acc[nf][r] - mrun[r]);   // <= 1
                lsum[r] += p;
                P_buf[w][row][nf*16 + lr] = (HF)p;
            }
        }

        // PV: Y[16 n][256 c] += P(16x32) @ G_chunk^T
        v4h plo = *(const v4h*)(&P_buf[w][lr][lkg*8]);
        v4h phi = *(const v4h*)(&P_buf[w][lr][lkg*8 + 4]);
        v8h ap = __builtin_shufflevector(plo, phi, 0,1,2,3,4,5,6,7);
        __builtin_amdgcn_s_setprio(1);
        #pragma unroll
        for (int cf = 0; cf < 16; ++cf) {
            v8h bg = *(const v8h*)(G_lds[cur] + lkg*2048 + (cf*16 + lr)*8);
            acc_y[cf] = __builtin_amdgcn_mfma_f32_16x16x32_f16(ap, bg, acc_y[cf], 0, 0, 0);
        }
        __builtin_amdgcn_s_setprio(0);

        __syncthreads();
        cur ^= 1;
    }

    // epilogue: one cross-lane sum reduce, then Y /= l
    HF* Yb = Yt + ((long)b*HW + nbase) * CI;
    #pragma unroll
    for (int r = 0; r < 4; ++r) {
        float s = lsum[r];
        #pragma unroll
        for (int d = 1; d < 16; d <<= 1) s += __shfl_xor(s, d);
        float inv = 1.f / s;
        #pragma unroll
        for (int cf = 0; cf < 16; ++cf)
            Yb[(long)(lkg*4 + r)*CI + cf*16 + lr] = (HF)(acc_y[cf][r] * inv);
    }
}

extern "C" void kernel_launch(void* const* d_in, const int* in_sizes, int n_in,
                              void* d_out, int out_size, void* d_ws, size_t ws_size,
                              hipStream_t stream)
{
    const float* x     = (const float*)d_in[0];
    const float* w_g   = (const float*)d_in[1];
    const float* b_g   = (const float*)d_in[2];
    const float* w_th  = (const float*)d_in[3];
    const float* b_th  = (const float*)d_in[4];
    const float* w_ph  = (const float*)d_in[5];
    const float* b_ph  = (const float*)d_in[6];
    const float* w_out = (const float*)d_in[7];
    const float* b_out = (const float*)d_in[8];
    const float* gamma = (const float*)d_in[9];
    const float* beta  = (const float*)d_in[10];
    const float* mean  = (const float*)d_in[11];
    const float* var   = (const float*)d_in[12];
    float* out = (float*)d_out;

    char* ws = (char*)d_ws;
    size_t off = 0;
    auto alloc = [&](size_t bytes) { void* p = ws + off; off += (bytes + 255) & ~(size_t)255; return p; };
    HF*    wall  = (HF*)alloc((size_t)768*512*2);
    float* ball  = (float*)alloc(768*4);
    HF*    wo    = (HF*)alloc((size_t)512*256*2);
    float* scale = (float*)alloc(512*4);
    float* shift = (float*)alloc(512*4);
    HF*    xT    = (HF*)alloc((size_t)Bn*HW*Cc*2);
    HF*    Full  = (HF*)alloc((size_t)Bn*768*HW*2);
    HF*    Tt    = (HF*)alloc((size_t)Bn*HW*CI*2);
    HF*    Pn    = (HF*)alloc((size_t)Bn*CI*Mp*2);
    HF*    Pt    = (HF*)alloc((size_t)Bn*Mp*CI*2);
    HF*    G     = (HF*)alloc((size_t)Bn*CI*Mp*2);
    HF*    Yt    = (HF*)alloc((size_t)Bn*HW*CI*2);

    prep_kernel<<<1536, 256, 0, stream>>>(w_g,b_g,w_th,b_th,w_ph,b_ph,w_out,b_out,gamma,beta,mean,var,
                                          wall, ball, wo, scale, shift);
    transpose_x_kernel<<<dim3(64,8,Bn), 256, 0, stream>>>(x, xT);
    // projections: Full[b, o, s], o: [0,256)=theta, [256,512)=phi, [512,768)=g
    gemm_bt_kernel<0><<<dim3(32,6,Bn), 256, 0, stream>>>(wall, 0, xT, (long)HW*Cc, Full, (long)768*HW,
                                                         768, HW, Cc, ball, nullptr, nullptr, nullptr, 0);
    // theta -> Tt[b, n, c]
    transpose_h_kernel<<<dim3(64,4,Bn), 256, 0, stream>>>(Full, (long)768*HW, Tt, (long)HW*CI, CI, HW);
    // phi -> pooled Pn[b, c, m] -> Pt[b, m, c]
    pool_kernel<<<8192, 256, 0, stream>>>(Full + (size_t)256*HW, (long)768*HW, Pn, (long)CI*Mp);
    transpose_h_kernel<<<dim3(16,4,Bn), 256, 0, stream>>>(Pn, (long)CI*Mp, Pt, (long)Mp*CI, CI, Mp);
    // g -> pooled G[b, c, m]
    pool_kernel<<<8192, 256, 0, stream>>>(Full + (size_t)512*HW, (long)768*HW, G, (long)CI*Mp);
    // fused scores+softmax+PV -> Yt[b, n, c]
    fused_attn_kernel<<<dim3(64,Bn), 256, 0, stream>>>(Tt, Pt, G, Yt);
    // out[b, co, n] = wo @ Yt^T * scale + shift + x
    gemm_bt_kernel<2><<<dim3(32,4,Bn), 256, 0, stream>>>(wo, 0, Yt, (long)HW*CI, out, (long)Cc*HW,
                                                         Cc, HW, CI, nullptr, scale, shift, x, (long)Cc*HW);
}